// Round 2
// baseline (246.270 us; speedup 1.0000x reference)
//
#include <hip/hip_runtime.h>

#define NN 100000
#define DD 128
#define HH 256
#define NE 600000
#define CAP 32   // max in-degree bucket capacity; Poisson(mean 6) => P(>=32) ~ 4e-16

typedef short bf8 __attribute__((ext_vector_type(8)));       // 8 bf16 (4 VGPRs)
typedef float f32x4 __attribute__((ext_vector_type(4)));     // MFMA C/D
typedef unsigned short u16x8 __attribute__((ext_vector_type(8)));

__device__ __forceinline__ unsigned short f2bf(float f) {
  unsigned int u = __builtin_bit_cast(unsigned int, f);
  u += 0x7fffu + ((u >> 16) & 1u);          // RNE
  return (unsigned short)(u >> 16);
}
__device__ __forceinline__ float bf2f(unsigned short h) {
  unsigned int u = ((unsigned int)h) << 16;
  return __builtin_bit_cast(float, u);
}

// ---- pack: weight pack (80 blocks x 256) + cnt zero (memset launch folded in).
// P[((nt*(K/32)+kt)*64 + lane)*8 + j] = W[kt*32+(lane>>4)*8+j][nt*16+(lane&15)]
__global__ __launch_bounds__(256) void pack(
    const float* __restrict__ Wm1, const float* __restrict__ Wm2,
    const float* __restrict__ Wn1, const float* __restrict__ Wn2,
    unsigned short* __restrict__ Pm1, unsigned short* __restrict__ Pm2,
    unsigned short* __restrict__ Pn1, unsigned short* __restrict__ Pn2,
    int* __restrict__ cnt) {
  int b = blockIdx.x;
  int gid = b * 256 + threadIdx.x;
  for (int i = gid; i < NN; i += 80 * 256) cnt[i] = 0;

  const float* W; unsigned short* P; int K, N, base;
  if (b < 16)      { W = Wm1; P = Pm1; K = 128; N = 256; base = 0;  }
  else if (b < 32) { W = Wm2; P = Pm2; K = 256; N = 128; base = 16; }
  else if (b < 64) { W = Wn1; P = Pn1; K = 256; N = 256; base = 32; }
  else             { W = Wn2; P = Pn2; K = 256; N = 128; base = 64; }
  int idx = (b - base) * 256 + threadIdx.x;
  int KT = K >> 5;
  int lane = idx & 63;
  int t = idx >> 6;
  int kt = t % KT, nt = t / KT;
  int n = nt * 16 + (lane & 15);
  int k0 = kt * 32 + (lane >> 4) * 8;
  unsigned short* dst = P + (size_t)idx * 8;
#pragma unroll
  for (int j = 0; j < 8; ++j) dst[j] = f2bf(W[(size_t)(k0 + j) * N + n]);
}

// ---- message MLP (512 thr, 8 waves, 64 rows); edge-bucket fill at HEAD ----
// (fill at head: atomic latency overlaps the block's own compute — r5/r6 A/B)
// Stages fp32 nodes -> bf16 LDS in-register.
__global__ __launch_bounds__(512) void msg_mlp(
    const float* __restrict__ nodes,
    const unsigned short* __restrict__ W1p, const float* __restrict__ b1,
    const unsigned short* __restrict__ W2p, const float* __restrict__ b2,
    unsigned short* __restrict__ Mb,
    const int* __restrict__ snd, const int* __restrict__ rcv,
    int* __restrict__ cnt, int* __restrict__ ebuf) {
  __shared__ __align__(16) unsigned short h[64][264];
  const int row0 = blockIdx.x * 64;
  const int tid = threadIdx.x;
  const int lane = tid & 63, wave = tid >> 6;   // 0..7
  const int l15 = lane & 15, l4 = lane >> 4;

  // folded CSR bucket fill (one edge per thread), overlapped with staging
  {
    int e = blockIdx.x * 512 + tid;
    if (e < NE) {
      int r = rcv[e];
      int pos = atomicAdd(&cnt[r], 1);
      if (pos < CAP) ebuf[r * CAP + pos] = snd[e];
    }
  }

  // stage X tile (64x128), fp32 -> bf16 in-register
#pragma unroll
  for (int i = 0; i < 2; ++i) {
    int flat = (i * 512 + tid) * 8;
    int r = flat >> 7, c = flat & 127;
    u16x8 o = (u16x8)0;
    if (row0 + r < NN) {
      const float4 v0 = *(const float4*)(nodes + (size_t)(row0 + r) * DD + c);
      const float4 v1 = *(const float4*)(nodes + (size_t)(row0 + r) * DD + c + 4);
      o[0] = f2bf(v0.x); o[1] = f2bf(v0.y); o[2] = f2bf(v0.z); o[3] = f2bf(v0.w);
      o[4] = f2bf(v1.x); o[5] = f2bf(v1.y); o[6] = f2bf(v1.z); o[7] = f2bf(v1.w);
    }
    *(u16x8*)&h[r][c] = o;
  }
  __syncthreads();

  // layer 1 (transposed): D[H=256][node=64], K=128. Wave owns 32 H rows.
  f32x4 acc[2][4];
#pragma unroll
  for (int mt = 0; mt < 2; ++mt)
#pragma unroll
    for (int nt = 0; nt < 4; ++nt) acc[mt][nt] = (f32x4){0.f, 0.f, 0.f, 0.f};
#pragma unroll
  for (int kt = 0; kt < 4; ++kt) {
    bf8 wfr[2], xfr[4];
#pragma unroll
    for (int mt = 0; mt < 2; ++mt) {
      int Htile = wave * 2 + mt;
      wfr[mt] = *(const bf8*)(W1p + ((size_t)(Htile * 4 + kt) * 64 + lane) * 8);
    }
#pragma unroll
    for (int nt = 0; nt < 4; ++nt)
      xfr[nt] = *(const bf8*)&h[nt * 16 + l15][kt * 32 + l4 * 8];
#pragma unroll
    for (int mt = 0; mt < 2; ++mt)
#pragma unroll
      for (int nt = 0; nt < 4; ++nt)
        acc[mt][nt] = __builtin_amdgcn_mfma_f32_16x16x32_bf16(wfr[mt], xfr[nt], acc[mt][nt], 0, 0, 0);
  }
  __syncthreads();

  // epilogue 1: bias + relu, vectorized writes h[node][H]
#pragma unroll
  for (int mt = 0; mt < 2; ++mt) {
    int Hbase = wave * 32 + mt * 16 + l4 * 4;
    float4 bv = *(const float4*)(b1 + Hbase);
#pragma unroll
    for (int nt = 0; nt < 4; ++nt) {
      ushort4 o;
      float v0 = acc[mt][nt][0] + bv.x; o.x = f2bf(v0 > 0.f ? v0 : 0.f);
      float v1 = acc[mt][nt][1] + bv.y; o.y = f2bf(v1 > 0.f ? v1 : 0.f);
      float v2 = acc[mt][nt][2] + bv.z; o.z = f2bf(v2 > 0.f ? v2 : 0.f);
      float v3 = acc[mt][nt][3] + bv.w; o.w = f2bf(v3 > 0.f ? v3 : 0.f);
      *(ushort4*)&h[nt * 16 + l15][Hbase] = o;
    }
  }
  __syncthreads();

  // layer 2 (transposed): D[Dout=128][node=64], K=256. Wave owns 16 Dout rows.
  f32x4 acc2[4];
#pragma unroll
  for (int nt = 0; nt < 4; ++nt) acc2[nt] = (f32x4){0.f, 0.f, 0.f, 0.f};
#pragma unroll
  for (int kt = 0; kt < 8; ++kt) {
    bf8 wfr, xfr[4];
    wfr = *(const bf8*)(W2p + ((size_t)(wave * 8 + kt) * 64 + lane) * 8);
#pragma unroll
    for (int nt = 0; nt < 4; ++nt)
      xfr[nt] = *(const bf8*)&h[nt * 16 + l15][kt * 32 + l4 * 8];
#pragma unroll
    for (int nt = 0; nt < 4; ++nt)
      acc2[nt] = __builtin_amdgcn_mfma_f32_16x16x32_bf16(wfr, xfr[nt], acc2[nt], 0, 0, 0);
  }
  // epilogue 2: bias + store Mb bf16
  {
    int Dbase = wave * 16 + l4 * 4;
    float4 bv = *(const float4*)(b2 + Dbase);
#pragma unroll
    for (int nt = 0; nt < 4; ++nt) {
      int node = row0 + nt * 16 + l15;
      if (node < NN) {
        ushort4 o;
        o.x = f2bf(acc2[nt][0] + bv.x);
        o.y = f2bf(acc2[nt][1] + bv.y);
        o.z = f2bf(acc2[nt][2] + bv.z);
        o.w = f2bf(acc2[nt][3] + bv.w);
        *(ushort4*)(Mb + (size_t)node * DD + Dbase) = o;
      }
    }
  }
}

// ---- node MLP fused with gather, gather pipelined under layer-1 X-half ----
// Layer1 K=256: k<128 reads X cols only, k>=128 reads agg cols only. So the
// 32 MFMAs of the X-half run while the random Mb gather loads are in flight.
// Residual from LDS bf16 tile (no fp32 nodes re-read: it was 51 MB of FETCH).
__global__ __launch_bounds__(512) void node_fused(
    const float* __restrict__ nodes, const unsigned short* __restrict__ Mb,
    const int* __restrict__ ebuf, const int* __restrict__ cnt,
    const unsigned short* __restrict__ W1p, const float* __restrict__ b1,
    const unsigned short* __restrict__ W2p, const float* __restrict__ b2,
    float* __restrict__ out) {
  __shared__ __align__(16) unsigned short h[64][264];
  const int row0 = blockIdx.x * 64;
  const int tid = threadIdx.x;
  const int lane = tid & 63, wave = tid >> 6;   // 0..7
  const int l15 = lane & 15, l4 = lane >> 4;
  const int halfid = lane >> 5, sub = lane & 31;

  // degrees + sender-slot prefetch (half-wave per node, 4 nodes per half)
  int degv[4], basev[4], s1[4][8];
#pragma unroll
  for (int t = 0; t < 4; ++t) {
    int node = row0 + t * 16 + wave * 2 + halfid;
    int nodec = (node < NN) ? node : 0;
    basev[t] = nodec * CAP;
    int d = (node < NN) ? cnt[node] : 0;
    degv[t] = d < CAP ? d : CAP;
  }
#pragma unroll
  for (int t = 0; t < 4; ++t)
#pragma unroll
    for (int u = 0; u < 8; ++u) s1[t][u] = ebuf[basev[t] + u];

  // stage X tile (64x128), fp32 -> bf16 in-register, cols 0..127
#pragma unroll
  for (int i = 0; i < 2; ++i) {
    int flat = (i * 512 + tid) * 8;
    int r = flat >> 7, c = flat & 127;
    u16x8 o = (u16x8)0;
    if (row0 + r < NN) {
      const float4 v0 = *(const float4*)(nodes + (size_t)(row0 + r) * DD + c);
      const float4 v1 = *(const float4*)(nodes + (size_t)(row0 + r) * DD + c + 4);
      o[0] = f2bf(v0.x); o[1] = f2bf(v0.y); o[2] = f2bf(v0.z); o[3] = f2bf(v0.w);
      o[4] = f2bf(v1.x); o[5] = f2bf(v1.y); o[6] = f2bf(v1.z); o[7] = f2bf(v1.w);
    }
    *(u16x8*)&h[r][c] = o;
  }
  __syncthreads();

  f32x4 acc[2][4];
#pragma unroll
  for (int mt = 0; mt < 2; ++mt)
#pragma unroll
    for (int nt = 0; nt < 4; ++nt) acc[mt][nt] = (f32x4){0.f, 0.f, 0.f, 0.f};

  // --- preload W frags for kt=0,1 BEFORE the scatter batch (VMEM returns are
  //     in-order: anything issued after the slow batch waits behind it) ---
  bf8 wfrA[2][2];
#pragma unroll
  for (int kt = 0; kt < 2; ++kt)
#pragma unroll
    for (int mt = 0; mt < 2; ++mt)
      wfrA[kt][mt] = *(const bf8*)(W1p + ((size_t)((wave * 2 + mt) * 8 + kt) * 64 + lane) * 8);

  // --- issue gather batch A (t=0,1): 16 random 8B loads ---
  ushort4 mvA[2][8];
#pragma unroll
  for (int t = 0; t < 2; ++t)
#pragma unroll
    for (int u = 0; u < 8; ++u) {
      int sl = s1[t][u];
      sl = ((unsigned)sl >= NN) ? 0 : sl;   // clamp garbage from unused slots
      mvA[t][u] = *(const ushort4*)(Mb + (size_t)sl * DD + sub * 4);
    }

  // residual snapshot (bf16, before epilogue-1 overwrites h cols 0..127)
  const int Dbase = wave * 16 + l4 * 4;
  ushort4 resid[4];
#pragma unroll
  for (int nt = 0; nt < 4; ++nt)
    resid[nt] = *(ushort4*)&h[nt * 16 + l15][Dbase];

  // --- layer 1 X-half, phase 1: kt=0,1 (hides mvA latency) ---
#pragma unroll
  for (int kt = 0; kt < 2; ++kt) {
    bf8 xfr[4];
#pragma unroll
    for (int nt = 0; nt < 4; ++nt)
      xfr[nt] = *(const bf8*)&h[nt * 16 + l15][kt * 32 + l4 * 8];
#pragma unroll
    for (int mt = 0; mt < 2; ++mt)
#pragma unroll
      for (int nt = 0; nt < 4; ++nt)
        acc[mt][nt] = __builtin_amdgcn_mfma_f32_16x16x32_bf16(wfrA[kt][mt], xfr[nt], acc[mt][nt], 0, 0, 0);
  }

  // consume A
  float a[4][4];
#pragma unroll
  for (int t = 0; t < 2; ++t) {
    int deg = degv[t];
    float a0 = 0.f, a1 = 0.f, a2 = 0.f, a3 = 0.f;
#pragma unroll
    for (int u = 0; u < 8; ++u) {
      bool act = u < deg;
      a0 += act ? bf2f(mvA[t][u].x) : 0.f;
      a1 += act ? bf2f(mvA[t][u].y) : 0.f;
      a2 += act ? bf2f(mvA[t][u].z) : 0.f;
      a3 += act ? bf2f(mvA[t][u].w) : 0.f;
    }
    a[t][0] = a0; a[t][1] = a1; a[t][2] = a2; a[t][3] = a3;
  }

  // preload W frags kt=2,3, then issue gather batch B (t=2,3)
  bf8 wfrB[2][2];
#pragma unroll
  for (int kt = 0; kt < 2; ++kt)
#pragma unroll
    for (int mt = 0; mt < 2; ++mt)
      wfrB[kt][mt] = *(const bf8*)(W1p + ((size_t)((wave * 2 + mt) * 8 + kt + 2) * 64 + lane) * 8);
  ushort4 mvB[2][8];
#pragma unroll
  for (int t = 0; t < 2; ++t)
#pragma unroll
    for (int u = 0; u < 8; ++u) {
      int sl = s1[t + 2][u];
      sl = ((unsigned)sl >= NN) ? 0 : sl;
      mvB[t][u] = *(const ushort4*)(Mb + (size_t)sl * DD + sub * 4);
    }

  // --- layer 1 X-half, phase 2: kt=2,3 (hides mvB latency) ---
#pragma unroll
  for (int kt = 2; kt < 4; ++kt) {
    bf8 xfr[4];
#pragma unroll
    for (int nt = 0; nt < 4; ++nt)
      xfr[nt] = *(const bf8*)&h[nt * 16 + l15][kt * 32 + l4 * 8];
#pragma unroll
    for (int mt = 0; mt < 2; ++mt)
#pragma unroll
      for (int nt = 0; nt < 4; ++nt)
        acc[mt][nt] = __builtin_amdgcn_mfma_f32_16x16x32_bf16(wfrB[kt - 2][mt], xfr[nt], acc[mt][nt], 0, 0, 0);
  }

  // consume B
#pragma unroll
  for (int t = 2; t < 4; ++t) {
    int deg = degv[t];
    float a0 = 0.f, a1 = 0.f, a2 = 0.f, a3 = 0.f;
#pragma unroll
    for (int u = 0; u < 8; ++u) {
      bool act = u < deg;
      a0 += act ? bf2f(mvB[t - 2][u].x) : 0.f;
      a1 += act ? bf2f(mvB[t - 2][u].y) : 0.f;
      a2 += act ? bf2f(mvB[t - 2][u].z) : 0.f;
      a3 += act ? bf2f(mvB[t - 2][u].w) : 0.f;
    }
    a[t][0] = a0; a[t][1] = a1; a[t][2] = a2; a[t][3] = a3;
  }

  // tails (deg > 8, ~15% of nodes): serial, other waves' MFMAs cover
#pragma unroll
  for (int t = 0; t < 4; ++t) {
    int deg = degv[t];
    for (int bb = 8; bb < deg; bb += 8) {
      int s[8]; ushort4 mv[8];
#pragma unroll
      for (int u = 0; u < 8; ++u) s[u] = ebuf[basev[t] + bb + u];
#pragma unroll
      for (int u = 0; u < 8; ++u) {
        int sl = s[u];
        sl = ((unsigned)sl >= NN) ? 0 : sl;
        mv[u] = *(const ushort4*)(Mb + (size_t)sl * DD + sub * 4);
      }
#pragma unroll
      for (int u = 0; u < 8; ++u) {
        bool act = (bb + u) < deg;
        a[t][0] += act ? bf2f(mv[u].x) : 0.f;
        a[t][1] += act ? bf2f(mv[u].y) : 0.f;
        a[t][2] += act ? bf2f(mv[u].z) : 0.f;
        a[t][3] += act ? bf2f(mv[u].w) : 0.f;
      }
    }
  }

  // write agg to LDS cols 128..255 (disjoint from X-half reads — no race)
#pragma unroll
  for (int t = 0; t < 4; ++t) {
    int ln = t * 16 + wave * 2 + halfid;
    ushort4 o;
    o.x = f2bf(a[t][0]); o.y = f2bf(a[t][1]);
    o.z = f2bf(a[t][2]); o.w = f2bf(a[t][3]);
    *(ushort4*)&h[ln][128 + sub * 4] = o;
  }
  __syncthreads();

  // --- layer 1 agg-half: kt=4..7 ---
#pragma unroll
  for (int kt = 4; kt < 8; ++kt) {
    bf8 wfr[2], xfr[4];
#pragma unroll
    for (int mt = 0; mt < 2; ++mt)
      wfr[mt] = *(const bf8*)(W1p + ((size_t)((wave * 2 + mt) * 8 + kt) * 64 + lane) * 8);
#pragma unroll
    for (int nt = 0; nt < 4; ++nt)
      xfr[nt] = *(const bf8*)&h[nt * 16 + l15][kt * 32 + l4 * 8];
#pragma unroll
    for (int mt = 0; mt < 2; ++mt)
#pragma unroll
      for (int nt = 0; nt < 4; ++nt)
        acc[mt][nt] = __builtin_amdgcn_mfma_f32_16x16x32_bf16(wfr[mt], xfr[nt], acc[mt][nt], 0, 0, 0);
  }
  __syncthreads();

  // epilogue 1: bias + relu
#pragma unroll
  for (int mt = 0; mt < 2; ++mt) {
    int Hbase = wave * 32 + mt * 16 + l4 * 4;
    float4 bv = *(const float4*)(b1 + Hbase);
#pragma unroll
    for (int nt = 0; nt < 4; ++nt) {
      ushort4 o;
      float v0 = acc[mt][nt][0] + bv.x; o.x = f2bf(v0 > 0.f ? v0 : 0.f);
      float v1 = acc[mt][nt][1] + bv.y; o.y = f2bf(v1 > 0.f ? v1 : 0.f);
      float v2 = acc[mt][nt][2] + bv.z; o.z = f2bf(v2 > 0.f ? v2 : 0.f);
      float v3 = acc[mt][nt][3] + bv.w; o.w = f2bf(v3 > 0.f ? v3 : 0.f);
      *(ushort4*)&h[nt * 16 + l15][Hbase] = o;
    }
  }
  __syncthreads();

  // layer 2 (transposed): D[Dout=128][node=64], K=256. Wave owns 16 Dout rows.
  f32x4 acc2[4];
#pragma unroll
  for (int nt = 0; nt < 4; ++nt) acc2[nt] = (f32x4){0.f, 0.f, 0.f, 0.f};
#pragma unroll
  for (int kt = 0; kt < 8; ++kt) {
    bf8 wfr, xfr[4];
    wfr = *(const bf8*)(W2p + ((size_t)(wave * 8 + kt) * 64 + lane) * 8);
#pragma unroll
    for (int nt = 0; nt < 4; ++nt)
      xfr[nt] = *(const bf8*)&h[nt * 16 + l15][kt * 32 + l4 * 8];
#pragma unroll
    for (int nt = 0; nt < 4; ++nt)
      acc2[nt] = __builtin_amdgcn_mfma_f32_16x16x32_bf16(wfr, xfr[nt], acc2[nt], 0, 0, 0);
  }
  // epilogue: bias + bf16 residual + coalesced float4 stores
  {
    float4 bv = *(const float4*)(b2 + Dbase);
#pragma unroll
    for (int nt = 0; nt < 4; ++nt) {
      int node = row0 + nt * 16 + l15;
      if (node < NN) {
        float4 o;
        o.x = bf2f(resid[nt].x) + acc2[nt][0] + bv.x;
        o.y = bf2f(resid[nt].y) + acc2[nt][1] + bv.y;
        o.z = bf2f(resid[nt].z) + acc2[nt][2] + bv.z;
        o.w = bf2f(resid[nt].w) + acc2[nt][3] + bv.w;
        *(float4*)(out + (size_t)node * DD + Dbase) = o;
      }
    }
  }
}

extern "C" void kernel_launch(void* const* d_in, const int* in_sizes, int n_in,
                              void* d_out, int out_size, void* d_ws, size_t ws_size,
                              hipStream_t stream) {
  const float* nodes = (const float*)d_in[0];
  const int* senders = (const int*)d_in[1];
  const int* receivers = (const int*)d_in[2];
  const float* Wm1 = (const float*)d_in[3];
  const float* bm1 = (const float*)d_in[4];
  const float* Wm2 = (const float*)d_in[5];
  const float* bm2 = (const float*)d_in[6];
  const float* Wn1 = (const float*)d_in[7];
  const float* bn1 = (const float*)d_in[8];
  const float* Wn2 = (const float*)d_in[9];
  const float* bn2 = (const float*)d_in[10];
  float* out = (float*)d_out;

  char* ws = (char*)d_ws;
  unsigned short* Mb   = (unsigned short*)(ws);               // 25,600,000 B
  int* cnt    = (int*)(ws + 25600000);                        // 400,000 B
  int* ebuf   = (int*)(ws + 26000000);                        // 12,800,000 B (NN*CAP*4)
  unsigned short* Wm1p = (unsigned short*)(ws + 38800000);    // 65,536 B
  unsigned short* Wm2p = (unsigned short*)(ws + 38865536);    // 65,536 B
  unsigned short* Wn1p = (unsigned short*)(ws + 38931072);    // 131,072 B
  unsigned short* Wn2p = (unsigned short*)(ws + 39062144);    // 65,536 B

  pack<<<80, 256, 0, stream>>>(Wm1, Wm2, Wn1, Wn2, Wm1p, Wm2p, Wn1p, Wn2p, cnt);
  msg_mlp<<<1563, 512, 0, stream>>>(nodes, Wm1p, bm1, Wm2p, bm2, Mb,
                                    senders, receivers, cnt, ebuf);
  node_fused<<<1563, 512, 0, stream>>>(nodes, Mb, ebuf, cnt,
                                       Wn1p, bn1, Wn2p, bn2, out);
}

// Round 3
// 227.431 us; speedup vs baseline: 1.0828x; 1.0828x over previous
//
#include <hip/hip_runtime.h>

#define NN 100000
#define DD 128
#define HH 256
#define NE 600000
#define CAP 32   // max in-degree bucket capacity; Poisson(mean 6) => P(>=32) ~ 4e-16

typedef short bf8 __attribute__((ext_vector_type(8)));       // 8 bf16 (4 VGPRs)
typedef float f32x4 __attribute__((ext_vector_type(4)));     // MFMA C/D
typedef unsigned short u16x8 __attribute__((ext_vector_type(8)));

__device__ __forceinline__ unsigned short f2bf(float f) {
  unsigned int u = __builtin_bit_cast(unsigned int, f);
  u += 0x7fffu + ((u >> 16) & 1u);          // RNE
  return (unsigned short)(u >> 16);
}
__device__ __forceinline__ float bf2f(unsigned short h) {
  unsigned int u = ((unsigned int)h) << 16;
  return __builtin_bit_cast(float, u);
}

// ---- pack: weight pack (80 blocks x 256) + cnt zero (memset launch folded in).
// P[((nt*(K/32)+kt)*64 + lane)*8 + j] = W[kt*32+(lane>>4)*8+j][nt*16+(lane&15)]
__global__ __launch_bounds__(256) void pack(
    const float* __restrict__ Wm1, const float* __restrict__ Wm2,
    const float* __restrict__ Wn1, const float* __restrict__ Wn2,
    unsigned short* __restrict__ Pm1, unsigned short* __restrict__ Pm2,
    unsigned short* __restrict__ Pn1, unsigned short* __restrict__ Pn2,
    int* __restrict__ cnt) {
  int b = blockIdx.x;
  int gid = b * 256 + threadIdx.x;
  for (int i = gid; i < NN; i += 80 * 256) cnt[i] = 0;

  const float* W; unsigned short* P; int K, N, base;
  if (b < 16)      { W = Wm1; P = Pm1; K = 128; N = 256; base = 0;  }
  else if (b < 32) { W = Wm2; P = Pm2; K = 256; N = 128; base = 16; }
  else if (b < 64) { W = Wn1; P = Pn1; K = 256; N = 256; base = 32; }
  else             { W = Wn2; P = Pn2; K = 256; N = 128; base = 64; }
  int idx = (b - base) * 256 + threadIdx.x;
  int KT = K >> 5;
  int lane = idx & 63;
  int t = idx >> 6;
  int kt = t % KT, nt = t / KT;
  int n = nt * 16 + (lane & 15);
  int k0 = kt * 32 + (lane >> 4) * 8;
  unsigned short* dst = P + (size_t)idx * 8;
#pragma unroll
  for (int j = 0; j < 8; ++j) dst[j] = f2bf(W[(size_t)(k0 + j) * N + n]);
}

// ---- message MLP (512 thr, 8 waves, 64 rows); edge-bucket fill at HEAD ----
// Stages fp32 nodes -> bf16 in-register; mirrors the converted tile to Xb
// (streaming write on idle BW) so node_fused can stage L3-warm bf16 instead
// of cold fp32 (halves its stage bytes, drops its f2bf VALU).
__global__ __launch_bounds__(512) void msg_mlp(
    const float* __restrict__ nodes,
    const unsigned short* __restrict__ W1p, const float* __restrict__ b1,
    const unsigned short* __restrict__ W2p, const float* __restrict__ b2,
    unsigned short* __restrict__ Mb, unsigned short* __restrict__ Xb,
    const int* __restrict__ snd, const int* __restrict__ rcv,
    int* __restrict__ cnt, int* __restrict__ ebuf) {
  __shared__ __align__(16) unsigned short h[64][264];
  const int row0 = blockIdx.x * 64;
  const int tid = threadIdx.x;
  const int lane = tid & 63, wave = tid >> 6;   // 0..7
  const int l15 = lane & 15, l4 = lane >> 4;

  // folded CSR bucket fill (one edge per thread), overlapped with staging
  {
    int e = blockIdx.x * 512 + tid;
    if (e < NE) {
      int r = rcv[e];
      int pos = atomicAdd(&cnt[r], 1);
      if (pos < CAP) ebuf[r * CAP + pos] = snd[e];
    }
  }

  // stage X tile (64x128), fp32 -> bf16 in-register; mirror to Xb
#pragma unroll
  for (int i = 0; i < 2; ++i) {
    int flat = (i * 512 + tid) * 8;
    int r = flat >> 7, c = flat & 127;
    u16x8 o = (u16x8)0;
    if (row0 + r < NN) {
      const float4 v0 = *(const float4*)(nodes + (size_t)(row0 + r) * DD + c);
      const float4 v1 = *(const float4*)(nodes + (size_t)(row0 + r) * DD + c + 4);
      o[0] = f2bf(v0.x); o[1] = f2bf(v0.y); o[2] = f2bf(v0.z); o[3] = f2bf(v0.w);
      o[4] = f2bf(v1.x); o[5] = f2bf(v1.y); o[6] = f2bf(v1.z); o[7] = f2bf(v1.w);
      *(u16x8*)(Xb + (size_t)(row0 + r) * DD + c) = o;
    }
    *(u16x8*)&h[r][c] = o;
  }
  __syncthreads();

  // layer 1 (transposed): D[H=256][node=64], K=128. Wave owns 32 H rows.
  f32x4 acc[2][4];
#pragma unroll
  for (int mt = 0; mt < 2; ++mt)
#pragma unroll
    for (int nt = 0; nt < 4; ++nt) acc[mt][nt] = (f32x4){0.f, 0.f, 0.f, 0.f};
#pragma unroll
  for (int kt = 0; kt < 4; ++kt) {
    bf8 wfr[2], xfr[4];
#pragma unroll
    for (int mt = 0; mt < 2; ++mt) {
      int Htile = wave * 2 + mt;
      wfr[mt] = *(const bf8*)(W1p + ((size_t)(Htile * 4 + kt) * 64 + lane) * 8);
    }
#pragma unroll
    for (int nt = 0; nt < 4; ++nt)
      xfr[nt] = *(const bf8*)&h[nt * 16 + l15][kt * 32 + l4 * 8];
#pragma unroll
    for (int mt = 0; mt < 2; ++mt)
#pragma unroll
      for (int nt = 0; nt < 4; ++nt)
        acc[mt][nt] = __builtin_amdgcn_mfma_f32_16x16x32_bf16(wfr[mt], xfr[nt], acc[mt][nt], 0, 0, 0);
  }
  __syncthreads();

  // epilogue 1: bias + relu, vectorized writes h[node][H]
#pragma unroll
  for (int mt = 0; mt < 2; ++mt) {
    int Hbase = wave * 32 + mt * 16 + l4 * 4;
    float4 bv = *(const float4*)(b1 + Hbase);
#pragma unroll
    for (int nt = 0; nt < 4; ++nt) {
      ushort4 o;
      float v0 = acc[mt][nt][0] + bv.x; o.x = f2bf(v0 > 0.f ? v0 : 0.f);
      float v1 = acc[mt][nt][1] + bv.y; o.y = f2bf(v1 > 0.f ? v1 : 0.f);
      float v2 = acc[mt][nt][2] + bv.z; o.z = f2bf(v2 > 0.f ? v2 : 0.f);
      float v3 = acc[mt][nt][3] + bv.w; o.w = f2bf(v3 > 0.f ? v3 : 0.f);
      *(ushort4*)&h[nt * 16 + l15][Hbase] = o;
    }
  }
  __syncthreads();

  // layer 2 (transposed): D[Dout=128][node=64], K=256. Wave owns 16 Dout rows.
  f32x4 acc2[4];
#pragma unroll
  for (int nt = 0; nt < 4; ++nt) acc2[nt] = (f32x4){0.f, 0.f, 0.f, 0.f};
#pragma unroll
  for (int kt = 0; kt < 8; ++kt) {
    bf8 wfr, xfr[4];
    wfr = *(const bf8*)(W2p + ((size_t)(wave * 8 + kt) * 64 + lane) * 8);
#pragma unroll
    for (int nt = 0; nt < 4; ++nt)
      xfr[nt] = *(const bf8*)&h[nt * 16 + l15][kt * 32 + l4 * 8];
#pragma unroll
    for (int nt = 0; nt < 4; ++nt)
      acc2[nt] = __builtin_amdgcn_mfma_f32_16x16x32_bf16(wfr, xfr[nt], acc2[nt], 0, 0, 0);
  }
  // epilogue 2: bias + store Mb bf16
  {
    int Dbase = wave * 16 + l4 * 4;
    float4 bv = *(const float4*)(b2 + Dbase);
#pragma unroll
    for (int nt = 0; nt < 4; ++nt) {
      int node = row0 + nt * 16 + l15;
      if (node < NN) {
        ushort4 o;
        o.x = f2bf(acc2[nt][0] + bv.x);
        o.y = f2bf(acc2[nt][1] + bv.y);
        o.z = f2bf(acc2[nt][2] + bv.z);
        o.w = f2bf(acc2[nt][3] + bv.w);
        *(ushort4*)(Mb + (size_t)node * DD + Dbase) = o;
      }
    }
  }
}

// ---- node MLP fused with gather (round-1 structure: 52 VGPR, no pipelining
// past the 64-VGPR occupancy cliff). Stage from L3-warm Xb bf16; residual
// snapshot from LDS bf16 (no fp32 nodes re-read).
__global__ __launch_bounds__(512) void node_fused(
    const unsigned short* __restrict__ Xb, const unsigned short* __restrict__ Mb,
    const int* __restrict__ ebuf, const int* __restrict__ cnt,
    const unsigned short* __restrict__ W1p, const float* __restrict__ b1,
    const unsigned short* __restrict__ W2p, const float* __restrict__ b2,
    float* __restrict__ out) {
  __shared__ __align__(16) unsigned short h[64][264];
  const int row0 = blockIdx.x * 64;
  const int tid = threadIdx.x;
  const int lane = tid & 63, wave = tid >> 6;   // 0..7
  const int l15 = lane & 15, l4 = lane >> 4;
  const int halfid = lane >> 5, sub = lane & 31;

  // degrees + first-batch sender-slot prefetch (half-wave per node)
  int degv[4], basev[4], s1[4][8];
#pragma unroll
  for (int t = 0; t < 4; ++t) {
    int node = row0 + t * 16 + wave * 2 + halfid;
    int nodec = (node < NN) ? node : 0;
    basev[t] = nodec * CAP;
    int d = (node < NN) ? cnt[node] : 0;
    degv[t] = d < CAP ? d : CAP;
  }
#pragma unroll
  for (int t = 0; t < 4; ++t)
#pragma unroll
    for (int u = 0; u < 8; ++u) s1[t][u] = ebuf[basev[t] + u];

  // stage X tile (64x128 bf16) from Xb, cols 0..127
#pragma unroll
  for (int i = 0; i < 2; ++i) {
    int flat = (i * 512 + tid) * 8;
    int r = flat >> 7, c = flat & 127;
    u16x8 v = (u16x8)0;
    if (row0 + r < NN) v = *(const u16x8*)(Xb + (size_t)(row0 + r) * DD + c);
    *(u16x8*)&h[r][c] = v;
  }

  // gather: half-wave per node (ushort4/lane over 128 cols), 4 rounds -> cols 128..255
#pragma unroll
  for (int t = 0; t < 4; ++t) {
    int ln = t * 16 + wave * 2 + halfid;
    int deg = degv[t];
    float a0 = 0.f, a1 = 0.f, a2 = 0.f, a3 = 0.f;
    {
      ushort4 mv[8];
#pragma unroll
      for (int u = 0; u < 8; ++u) {
        int sl = s1[t][u];
        sl = ((unsigned)sl >= NN) ? 0 : sl;   // clamp garbage from unused slots
        mv[u] = *(const ushort4*)(Mb + (size_t)sl * DD + sub * 4);
      }
#pragma unroll
      for (int u = 0; u < 8; ++u) {
        bool act = u < deg;
        a0 += act ? bf2f(mv[u].x) : 0.f;
        a1 += act ? bf2f(mv[u].y) : 0.f;
        a2 += act ? bf2f(mv[u].z) : 0.f;
        a3 += act ? bf2f(mv[u].w) : 0.f;
      }
    }
    for (int bb = 8; bb < deg; bb += 8) {   // rare tail (deg > 8)
      int s[8]; ushort4 mv[8];
#pragma unroll
      for (int u = 0; u < 8; ++u) s[u] = ebuf[basev[t] + bb + u];
#pragma unroll
      for (int u = 0; u < 8; ++u) {
        int sl = s[u];
        sl = ((unsigned)sl >= NN) ? 0 : sl;
        mv[u] = *(const ushort4*)(Mb + (size_t)sl * DD + sub * 4);
      }
#pragma unroll
      for (int u = 0; u < 8; ++u) {
        bool act = (bb + u) < deg;
        a0 += act ? bf2f(mv[u].x) : 0.f;
        a1 += act ? bf2f(mv[u].y) : 0.f;
        a2 += act ? bf2f(mv[u].z) : 0.f;
        a3 += act ? bf2f(mv[u].w) : 0.f;
      }
    }
    ushort4 o;
    o.x = f2bf(a0); o.y = f2bf(a1); o.z = f2bf(a2); o.w = f2bf(a3);
    *(ushort4*)&h[ln][128 + sub * 4] = o;
  }
  __syncthreads();

  // residual snapshot (bf16, before epilogue-1 overwrites h cols 0..127)
  const int Dbase = wave * 16 + l4 * 4;
  ushort4 resid[4];
#pragma unroll
  for (int nt = 0; nt < 4; ++nt)
    resid[nt] = *(ushort4*)&h[nt * 16 + l15][Dbase];

  // layer 1 (transposed): D[H=256][node=64], K=256. Wave owns 32 H rows.
  f32x4 acc[2][4];
#pragma unroll
  for (int mt = 0; mt < 2; ++mt)
#pragma unroll
    for (int nt = 0; nt < 4; ++nt) acc[mt][nt] = (f32x4){0.f, 0.f, 0.f, 0.f};
#pragma unroll
  for (int kt = 0; kt < 8; ++kt) {
    bf8 wfr[2], xfr[4];
#pragma unroll
    for (int mt = 0; mt < 2; ++mt) {
      int Htile = wave * 2 + mt;
      wfr[mt] = *(const bf8*)(W1p + ((size_t)(Htile * 8 + kt) * 64 + lane) * 8);
    }
#pragma unroll
    for (int nt = 0; nt < 4; ++nt)
      xfr[nt] = *(const bf8*)&h[nt * 16 + l15][kt * 32 + l4 * 8];
#pragma unroll
    for (int mt = 0; mt < 2; ++mt)
#pragma unroll
      for (int nt = 0; nt < 4; ++nt)
        acc[mt][nt] = __builtin_amdgcn_mfma_f32_16x16x32_bf16(wfr[mt], xfr[nt], acc[mt][nt], 0, 0, 0);
  }
  __syncthreads();

  // epilogue 1: bias + relu
#pragma unroll
  for (int mt = 0; mt < 2; ++mt) {
    int Hbase = wave * 32 + mt * 16 + l4 * 4;
    float4 bv = *(const float4*)(b1 + Hbase);
#pragma unroll
    for (int nt = 0; nt < 4; ++nt) {
      ushort4 o;
      float v0 = acc[mt][nt][0] + bv.x; o.x = f2bf(v0 > 0.f ? v0 : 0.f);
      float v1 = acc[mt][nt][1] + bv.y; o.y = f2bf(v1 > 0.f ? v1 : 0.f);
      float v2 = acc[mt][nt][2] + bv.z; o.z = f2bf(v2 > 0.f ? v2 : 0.f);
      float v3 = acc[mt][nt][3] + bv.w; o.w = f2bf(v3 > 0.f ? v3 : 0.f);
      *(ushort4*)&h[nt * 16 + l15][Hbase] = o;
    }
  }
  __syncthreads();

  // layer 2 (transposed): D[Dout=128][node=64], K=256. Wave owns 16 Dout rows.
  f32x4 acc2[4];
#pragma unroll
  for (int nt = 0; nt < 4; ++nt) acc2[nt] = (f32x4){0.f, 0.f, 0.f, 0.f};
#pragma unroll
  for (int kt = 0; kt < 8; ++kt) {
    bf8 wfr, xfr[4];
    wfr = *(const bf8*)(W2p + ((size_t)(wave * 8 + kt) * 64 + lane) * 8);
#pragma unroll
    for (int nt = 0; nt < 4; ++nt)
      xfr[nt] = *(const bf8*)&h[nt * 16 + l15][kt * 32 + l4 * 8];
#pragma unroll
    for (int nt = 0; nt < 4; ++nt)
      acc2[nt] = __builtin_amdgcn_mfma_f32_16x16x32_bf16(wfr, xfr[nt], acc2[nt], 0, 0, 0);
  }
  // epilogue: bias + bf16 residual + coalesced float4 stores
  {
    float4 bv = *(const float4*)(b2 + Dbase);
#pragma unroll
    for (int nt = 0; nt < 4; ++nt) {
      int node = row0 + nt * 16 + l15;
      if (node < NN) {
        float4 o;
        o.x = bf2f(resid[nt].x) + acc2[nt][0] + bv.x;
        o.y = bf2f(resid[nt].y) + acc2[nt][1] + bv.y;
        o.z = bf2f(resid[nt].z) + acc2[nt][2] + bv.z;
        o.w = bf2f(resid[nt].w) + acc2[nt][3] + bv.w;
        *(float4*)(out + (size_t)node * DD + Dbase) = o;
      }
    }
  }
}

extern "C" void kernel_launch(void* const* d_in, const int* in_sizes, int n_in,
                              void* d_out, int out_size, void* d_ws, size_t ws_size,
                              hipStream_t stream) {
  const float* nodes = (const float*)d_in[0];
  const int* senders = (const int*)d_in[1];
  const int* receivers = (const int*)d_in[2];
  const float* Wm1 = (const float*)d_in[3];
  const float* bm1 = (const float*)d_in[4];
  const float* Wm2 = (const float*)d_in[5];
  const float* bm2 = (const float*)d_in[6];
  const float* Wn1 = (const float*)d_in[7];
  const float* bn1 = (const float*)d_in[8];
  const float* Wn2 = (const float*)d_in[9];
  const float* bn2 = (const float*)d_in[10];
  float* out = (float*)d_out;

  char* ws = (char*)d_ws;
  unsigned short* Mb   = (unsigned short*)(ws);               // 25,600,000 B
  unsigned short* Xb   = (unsigned short*)(ws + 25600000);    // 25,600,000 B
  int* cnt    = (int*)(ws + 51200000);                        // 400,000 B
  int* ebuf   = (int*)(ws + 51600000);                        // 12,800,000 B (NN*CAP*4)
  unsigned short* Wm1p = (unsigned short*)(ws + 64400000);    // 65,536 B
  unsigned short* Wm2p = (unsigned short*)(ws + 64465536);    // 65,536 B
  unsigned short* Wn1p = (unsigned short*)(ws + 64531072);    // 131,072 B
  unsigned short* Wn2p = (unsigned short*)(ws + 64662144);    // 65,536 B

  pack<<<80, 256, 0, stream>>>(Wm1, Wm2, Wn1, Wn2, Wm1p, Wm2p, Wn1p, Wn2p, cnt);
  msg_mlp<<<1563, 512, 0, stream>>>(nodes, Wm1p, bm1, Wm2p, bm2, Mb, Xb,
                                    senders, receivers, cnt, ebuf);
  node_fused<<<1563, 512, 0, stream>>>(Xb, Mb, ebuf, cnt,
                                       Wn1p, bn1, Wn2p, bn2, out);
}